// Round 5
// baseline (3048.707 us; speedup 1.0000x reference)
//
#include <hip/hip_runtime.h>

#define HW 65536
#define RSTRIDE 68   // floats per private LDS row; 272 B, 16B-aligned, measured conflict-free

// cc[l*1024 + s*256 + m] = ||cb[l,s,m,:]||^2  (4-partial order matches main kernel)
__global__ void cc_kernel(const float* __restrict__ cbk, float* __restrict__ cc) {
    const int i = blockIdx.x * 256 + threadIdx.x;
    if (i < 3072) {
        const float* p = cbk + (size_t)i * 16;
        float s0 = 0.f, s1 = 0.f, s2 = 0.f, s3 = 0.f;
        #pragma unroll
        for (int d4 = 0; d4 < 4; ++d4) {
            const float4 v = *(const float4*)(p + 4 * d4);
            s0 = fmaf(v.x, v.x, s0); s1 = fmaf(v.y, v.y, s1);
            s2 = fmaf(v.z, v.z, s2); s3 = fmaf(v.w, v.w, s3);
        }
        cc[i] = (s0 + s1) + (s2 + s3);
    }
}

// acc[c] = sum_k my[k]*W[k][c] + b[c].  my = per-lane LDS row (ds_read_b128,
// 16 per call); W/b wave-uniform -> scalar loads feeding v_fma's SGPR operand.
__device__ __forceinline__ void mm64(const float* __restrict__ my,
                                     const float* __restrict__ Wl,
                                     const float* __restrict__ bl,
                                     float (&acc)[64])
{
    #pragma unroll
    for (int c = 0; c < 64; ++c) acc[c] = 0.f;
    for (int k4 = 0; k4 < 16; ++k4) {              // dynamic: keeps code small
        const float4 a = *(const float4*)(my + 4 * k4);
        const float* __restrict__ wr = Wl + (4 * k4) * 64;
        #pragma unroll
        for (int c = 0; c < 64; ++c) acc[c] = fmaf(a.x, wr[c],       acc[c]);
        #pragma unroll
        for (int c = 0; c < 64; ++c) acc[c] = fmaf(a.y, wr[64 + c],  acc[c]);
        #pragma unroll
        for (int c = 0; c < 64; ++c) acc[c] = fmaf(a.z, wr[128 + c], acc[c]);
        #pragma unroll
        for (int c = 0; c < 64; ++c) acc[c] = fmaf(a.w, wr[192 + c], acc[c]);
    }
    #pragma unroll
    for (int c = 0; c < 64; ++c) acc[c] += bl[c];
}

__device__ __forceinline__ void store_row(float* __restrict__ my,
                                          const float (&a)[64])
{
    #pragma unroll
    for (int i = 0; i < 16; ++i)
        *(float4*)(my + 4 * i) = make_float4(a[4*i], a[4*i+1], a[4*i+2], a[4*i+3]);
}

__global__ __launch_bounds__(256, 2)
void hpp_fused(const float* __restrict__ x,
               const float* __restrict__ W_enc, const float* __restrict__ b_enc,
               const float* __restrict__ W_qh,  const float* __restrict__ b_qh,
               const float* __restrict__ W_lh,  const float* __restrict__ b_lh,
               const float* __restrict__ W_dq,  const float* __restrict__ b_dq,
               const float* __restrict__ W_rh,  const float* __restrict__ b_rh,
               const float* __restrict__ cbk,   const float* __restrict__ ccws,
               float* __restrict__ out, float* __restrict__ loss_out)
{
    __shared__ __align__(16) float lds[256 * RSTRIDE];

    const int t    = threadIdx.x;
    const int lane = t & 63;
    const int row  = blockIdx.x * 256 + t;
    const int b    = row >> 16;
    const int hw   = row & (HW - 1);
    const size_t iobase = (size_t)b * (64 * HW) + hw;

    float* __restrict__ my = lds + t * RSTRIDE;

    // stage x: my[c] = x[b, c, hw]  (coalesced across lanes)
    for (int c4 = 0; c4 < 16; ++c4) {
        float4 v;
        v.x = x[iobase + (size_t)(4 * c4 + 0) * HW];
        v.y = x[iobase + (size_t)(4 * c4 + 1) * HW];
        v.z = x[iobase + (size_t)(4 * c4 + 2) * HW];
        v.w = x[iobase + (size_t)(4 * c4 + 3) * HW];
        *(float4*)(my + 4 * c4) = v;
    }

    float acc[64];   // z / q / quant / deq / rh-result
    float zl[64];    // z @ W_lh + b_lh, then next residual
    float loss_acc = 0.f;

    for (int L = 0; L < 3; ++L) {
        const int Lo = L * 4096;
        const int Lb = L * 64;

        // z = residual @ W_enc + b_enc
        mm64(my, W_enc + Lo, b_enc + Lb, acc);
        store_row(my, acc);                       // my = z
        // zl = z @ W_lh + b_lh (while my = z)
        if (L < 2) mm64(my, W_lh + Lo, b_lh + Lb, zl);
        // q = z @ W_qh + b_qh
        mm64(my, W_qh + Lo, b_qh + Lb, acc);

        // ---- VQ: per-lane scan; codebook/cc stream on the scalar pipe ----
        const float* __restrict__ cbL = cbk  + (size_t)L * 4 * 4096;
        const float* __restrict__ ccL = ccws + L * 1024;
        #pragma unroll
        for (int s = 0; s < 4; ++s) {
            const float* __restrict__ cbs = cbL + s * 4096;   // uniform
            const float* __restrict__ ccs = ccL + s * 256;    // uniform
            float qq = 0.f;
            #pragma unroll
            for (int d = 0; d < 16; ++d) qq = fmaf(acc[s * 16 + d], acc[s * 16 + d], qq);
            float best = 3.4e38f; int bi = 0;
            #pragma unroll 4
            for (int m = 0; m < 256; ++m) {
                const float* __restrict__ cp = cbs + m * 16;
                float d0 = 0.f, d1 = 0.f, d2 = 0.f, d3 = 0.f;
                #pragma unroll
                for (int d4 = 0; d4 < 4; ++d4) {
                    d0 = fmaf(acc[s * 16 + 4 * d4 + 0], cp[4 * d4 + 0], d0);
                    d1 = fmaf(acc[s * 16 + 4 * d4 + 1], cp[4 * d4 + 1], d1);
                    d2 = fmaf(acc[s * 16 + 4 * d4 + 2], cp[4 * d4 + 2], d2);
                    d3 = fmaf(acc[s * 16 + 4 * d4 + 3], cp[4 * d4 + 3], d3);
                }
                const float dot  = (d0 + d1) + (d2 + d3);
                const float dist = qq - 2.0f * dot + ccs[m];  // exact expr of passing kernels
                if (dist < best) { best = dist; bi = m; }     // strict < : first-min
            }
            const float* __restrict__ hp = cbs + bi * 16;     // divergent gather, L1-hot
            #pragma unroll
            for (int d4 = 0; d4 < 4; ++d4) {
                const float4 h = *(const float4*)(hp + 4 * d4);
                float e;
                e = acc[s*16+4*d4+0] - h.x; loss_acc = fmaf(e, e, loss_acc); acc[s*16+4*d4+0] = h.x;
                e = acc[s*16+4*d4+1] - h.y; loss_acc = fmaf(e, e, loss_acc); acc[s*16+4*d4+1] = h.y;
                e = acc[s*16+4*d4+2] - h.z; loss_acc = fmaf(e, e, loss_acc); acc[s*16+4*d4+2] = h.z;
                e = acc[s*16+4*d4+3] - h.w; loss_acc = fmaf(e, e, loss_acc); acc[s*16+4*d4+3] = h.w;
            }
        }

        store_row(my, acc);                       // my = quant
        mm64(my, W_dq + Lo, b_dq + Lb, acc);      // acc = deq
        if (L < 2) {
            #pragma unroll
            for (int c = 0; c < 64; ++c) zl[c] -= acc[c];   // zl = next residual
        }
        store_row(my, acc);                       // my = deq
        mm64(my, W_rh + Lo, b_rh + Lb, acc);      // acc = deq @ W_rh + b_rh

        // restored lives in `out` (own row only -> race-free; L==0 overwrites poison)
        if (L == 0) {
            #pragma unroll
            for (int c = 0; c < 64; ++c)
                out[iobase + (size_t)c * HW] = acc[c];
        } else {
            #pragma unroll
            for (int c = 0; c < 64; ++c)
                out[iobase + (size_t)c * HW] += acc[c];
        }

        if (L < 2) store_row(my, zl);             // my = residual for next layer
    }

    // loss: per-wave shuffle reduce -> one atomic per wave
    #pragma unroll
    for (int off = 32; off > 0; off >>= 1) loss_acc += __shfl_down(loss_acc, off, 64);
    if (lane == 0)
        atomicAdd(loss_out, loss_acc * (1.25f / 16777216.0f));
}

extern "C" void kernel_launch(void* const* d_in, const int* in_sizes, int n_in,
                              void* d_out, int out_size, void* d_ws, size_t ws_size,
                              hipStream_t stream) {
    const float* x     = (const float*)d_in[0];
    const float* W_enc = (const float*)d_in[1];
    const float* b_enc = (const float*)d_in[2];
    const float* W_qh  = (const float*)d_in[3];
    const float* b_qh  = (const float*)d_in[4];
    const float* W_lh  = (const float*)d_in[5];
    const float* b_lh  = (const float*)d_in[6];
    const float* W_dq  = (const float*)d_in[7];
    const float* b_dq  = (const float*)d_in[8];
    const float* W_rh  = (const float*)d_in[9];
    const float* b_rh  = (const float*)d_in[10];
    const float* cbk   = (const float*)d_in[11];

    float* out      = (float*)d_out;
    float* loss_out = out + (out_size - 1);
    float* ccws     = (float*)d_ws;           // 3072 floats

    hipMemsetAsync(loss_out, 0, sizeof(float), stream);
    cc_kernel<<<dim3(12), dim3(256), 0, stream>>>(cbk, ccws);
    hpp_fused<<<dim3(1024), dim3(256), 0, stream>>>(
        x, W_enc, b_enc, W_qh, b_qh, W_lh, b_lh, W_dq, b_dq, W_rh, b_rh,
        cbk, ccws, out, loss_out);
}